// Round 1
// 254.756 us; speedup vs baseline: 1.2387x; 1.2387x over previous
//
#include <hip/hip_runtime.h>

#define NNODES 50000
#define FDIM 128
#define KELL 40

typedef float f4 __attribute__((ext_vector_type(4)));
typedef float f2 __attribute__((ext_vector_type(2)));
typedef short short8 __attribute__((ext_vector_type(8)));
typedef uint uint4v __attribute__((ext_vector_type(4)));
typedef uint uint2v __attribute__((ext_vector_type(2)));

// ---- single-pass ELL fill, 2 edges/thread for atomic MLP ----
// Degrees ~Poisson(12): P(deg>40)*50k ~ 5e-6, slot clamped for safety.
__global__ __launch_bounds__(256) void k_fill(const int* __restrict__ src,
                                              const int* __restrict__ dst,
                                              int* __restrict__ fill,
                                              int* __restrict__ col, int E) {
    int i = blockIdx.x * 256 + threadIdx.x;
    int e0 = i * 2;
    if (e0 + 1 < E) {
        int2 s2 = *(const int2*)(src + e0);
        int2 d2 = *(const int2*)(dst + e0);
        int slot0 = atomicAdd(&fill[d2.x], 1);
        int slot1 = atomicAdd(&fill[d2.y], 1);
        if (slot0 < KELL) col[d2.x * KELL + slot0] = s2.x;
        if (slot1 < KELL) col[d2.y * KELL + slot1] = s2.y;
    } else if (e0 < E) {
        int d = dst[e0];
        int slot = atomicAdd(&fill[d], 1);
        if (slot < KELL) col[d * KELL + slot] = src[e0];
    }
}

// ---- split one f32 pair into packed truncated-bf16 hi / lo words ----
__device__ __forceinline__ void split2(float x0, float x1, unsigned& hi, unsigned& lo) {
    unsigned u0 = __float_as_uint(x0), u1 = __float_as_uint(x1);
    unsigned h0 = u0 & 0xffff0000u, h1 = u1 & 0xffff0000u;
    hi = h1 | (h0 >> 16);
    float l0 = x0 - __uint_as_float(h0);
    float l1 = x1 - __uint_as_float(h1);
    lo = (__float_as_uint(l1) & 0xffff0000u) | (__float_as_uint(l0) >> 16);
}

// ---- pack two f32 accumulators into one uint of 2x RTNE bf16 ----
__device__ __forceinline__ unsigned pack2(float lo, float hi) {
    unsigned ul = __float_as_uint(lo);
    unsigned uh = __float_as_uint(hi);
    ul += 0x7fffu + ((ul >> 16) & 1u);   // round-to-nearest-even into bf16
    uh += 0x7fffu + ((uh >> 16) & 1u);
    return (ul >> 16) | (uh & 0xffff0000u);
}

// ---- decode a gathered uint2 (4 packed bf16) back to f4 ----
__device__ __forceinline__ f4 dec(uint2v v) {
    f4 r;
    r.x = __uint_as_float(v.x << 16);
    r.y = __uint_as_float(v.x & 0xffff0000u);
    r.z = __uint_as_float(v.y << 16);
    r.w = __uint_as_float(v.y & 0xffff0000u);
    return r;
}

// ---- W pre-split into MFMA B-fragment order (hi 8192 uints, lo 8192 uints) ----
// B-frag for mfma_f32_16x16x32_bf16: lane l, reg j holds W[k][n],
// k=(l>>4)*8+j+32*s, n=t*16+(l&15). Packed record: uint p = ((s*8+t)*64+l)*4+jp
// holds bf16 pair (j=2jp, 2jp+1) -> lane-contiguous dwordx4, L2-broadcast.
__global__ __launch_bounds__(256) void k_prepw(const float* __restrict__ W1,
                                               const float* __restrict__ W2,
                                               const float* __restrict__ W3,
                                               unsigned* __restrict__ wpk) {
    int y = blockIdx.y;
    const float* W = (y == 0) ? W1 : (y == 1) ? W2 : W3;
    unsigned* dh = wpk + (size_t)y * 16384;
    unsigned* dl = dh + 8192;
    int p = blockIdx.x * 256 + threadIdx.x;     // 0..8191
    int jp = p & 3;
    int l = (p >> 2) & 63;
    int st = p >> 8;                            // s*8 + t
    int s = st >> 3, t = st & 7;
    int k0 = ((l >> 4) << 3) + (jp << 1) + (s << 5);
    int n = (t << 4) + (l & 15);
    float x0 = W[k0 * 128 + n];
    float x1 = W[(k0 + 1) * 128 + n];
    unsigned hi, lo;
    split2(x0, x1, hi, lo);
    dh[p] = hi;
    dl[p] = lo;
}

// ---- MFMA GEMM: no LDS, B-frags stream from L2 (same addr across waves).
// EVERYTHING fully unrolled: runtime-indexed register arrays get demoted to
// scratch (rule: static indices only). __launch_bounds__(256,4) caps VGPRs at
// 128 -> 16 waves/CU.
// Output h is consumed ONLY by aggregation (which is linear per-column), so we
// store it as RTNE bf16, column-pair packed: uint p = u*16+m16 of row rr holds
// (lo = col 32u+m16, hi = col 32u+16+m16). Halves h write traffic AND halves
// the aggregation's random-gather bytes (512B -> 256B per row).
__global__ __launch_bounds__(256, 4) void k_gemm(const float* __restrict__ A,
                                                 const unsigned* __restrict__ wsrc,
                                                 unsigned* __restrict__ H, int nrows) {
    int tid = threadIdx.x;
    int w = tid >> 6, l = tid & 63;
    int m16 = l & 15, q = l >> 4;
    int rbase = blockIdx.x * 64 + w * 16;
    int row = rbase + m16;
    int rowc = row > nrows - 1 ? nrows - 1 : row;

    union u8 { unsigned u[4]; uint4v uv; short8 v; };
    u8 ah[4], al[4];
    const f4* A4 = (const f4*)A;
#pragma unroll
    for (int s = 0; s < 4; ++s) {
        f4 a0 = A4[(size_t)rowc * 32 + s * 8 + q * 2];
        f4 a1 = A4[(size_t)rowc * 32 + s * 8 + q * 2 + 1];
        split2(a0.x, a0.y, ah[s].u[0], al[s].u[0]);
        split2(a0.z, a0.w, ah[s].u[1], al[s].u[1]);
        split2(a1.x, a1.y, ah[s].u[2], al[s].u[2]);
        split2(a1.z, a1.w, ah[s].u[3], al[s].u[3]);
    }

    f4 acc[8];
#pragma unroll
    for (int t = 0; t < 8; ++t) acc[t] = (f4)0.0f;

    const uint4v* wg4 = (const uint4v*)wsrc;    // hi: [0,2048) lo: [2048,4096)
#pragma unroll
    for (int s = 0; s < 4; ++s) {
#pragma unroll
        for (int t = 0; t < 8; ++t) {
            u8 bh, bl;
            bh.uv = wg4[(s * 8 + t) * 64 + l];
            bl.uv = wg4[2048 + (s * 8 + t) * 64 + l];
            acc[t] = __builtin_amdgcn_mfma_f32_16x16x32_bf16(ah[s].v, bh.v, acc[t], 0, 0, 0);
            acc[t] = __builtin_amdgcn_mfma_f32_16x16x32_bf16(al[s].v, bh.v, acc[t], 0, 0, 0);
            acc[t] = __builtin_amdgcn_mfma_f32_16x16x32_bf16(ah[s].v, bl.v, acc[t], 0, 0, 0);
        }
    }

    // D layout: col = lane&15, row = (lane>>4)*4 + reg
    // Pack col pair (t=2u, t=2u+1) -> one uint; 16 dword stores (64B/16-lane
    // segment), half the previous store count and write bytes.
#pragma unroll
    for (int u = 0; u < 4; ++u) {
#pragma unroll
        for (int r = 0; r < 4; ++r) {
            int rr = rbase + q * 4 + r;
            if (rr < nrows)
                H[(size_t)rr * 64 + u * 16 + m16] =
                    pack2(acc[2 * u][r], acc[2 * u + 1][r]);
        }
    }
}

// ---- aggregation: 2 nodes/wave, ELL segments, inline rsqrt for dinv ----
// out[n] = dinv[n]*( dinv[n]*h[n] + sum_s dinv[s]*h[s] ) + b,  dinv = rsqrt(1+deg)
// h rows are 256B packed bf16: lane sl gathers uint2 (8B) -> 4 cols
// {32u+m, 32u+16+m, 32u+m+1, 32u+16+m+1}, u=sl>>3, m=2*(sl&7).
// Output un-permutes back to standard f32 layout via two float2 stores.
__global__ __launch_bounds__(256) void k_agg(const unsigned* __restrict__ hpk,
                                             const int* __restrict__ fill,
                                             const int* __restrict__ col,
                                             const float* __restrict__ bias,
                                             float* __restrict__ out,
                                             float* __restrict__ out2, int relu) {
    int gw = (blockIdx.x * 256 + threadIdx.x) >> 6;
    int lane = threadIdx.x & 63;
    int half = lane >> 5;
    int sl = lane & 31;
    int hb = half * 32;
    int n = gw * 2 + half;
    if (n >= NNODES) return;
    int deg = fill[n];
    int c = deg < KELL ? deg : KELL;
    float di = rsqrtf(1.0f + (float)deg);

    const uint2v* h2 = (const uint2v*)hpk;
    f4 a = di * dec(h2[(size_t)n * 32 + sl]);

    int beg = n * KELL;
    {
        int cv = 0;
        float wv = 0.0f;
        if (sl < c) {
            cv = col[beg + sl];
            wv = rsqrtf(1.0f + (float)fill[cv]);
        }
        int j = 0;
#pragma unroll 1
        for (; j + 8 <= c; j += 8) {
            int s0 = __shfl(cv, hb + j);
            int s1 = __shfl(cv, hb + j + 1);
            int s2 = __shfl(cv, hb + j + 2);
            int s3 = __shfl(cv, hb + j + 3);
            int s4 = __shfl(cv, hb + j + 4);
            int s5 = __shfl(cv, hb + j + 5);
            int s6 = __shfl(cv, hb + j + 6);
            int s7 = __shfl(cv, hb + j + 7);
            float w0 = __shfl(wv, hb + j);
            float w1 = __shfl(wv, hb + j + 1);
            float w2 = __shfl(wv, hb + j + 2);
            float w3 = __shfl(wv, hb + j + 3);
            float w4 = __shfl(wv, hb + j + 4);
            float w5 = __shfl(wv, hb + j + 5);
            float w6 = __shfl(wv, hb + j + 6);
            float w7 = __shfl(wv, hb + j + 7);
            uint2v v0 = h2[(size_t)s0 * 32 + sl];
            uint2v v1 = h2[(size_t)s1 * 32 + sl];
            uint2v v2 = h2[(size_t)s2 * 32 + sl];
            uint2v v3 = h2[(size_t)s3 * 32 + sl];
            uint2v v4 = h2[(size_t)s4 * 32 + sl];
            uint2v v5 = h2[(size_t)s5 * 32 + sl];
            uint2v v6 = h2[(size_t)s6 * 32 + sl];
            uint2v v7 = h2[(size_t)s7 * 32 + sl];
            a += w0 * dec(v0); a += w1 * dec(v1); a += w2 * dec(v2); a += w3 * dec(v3);
            a += w4 * dec(v4); a += w5 * dec(v5); a += w6 * dec(v6); a += w7 * dec(v7);
        }
#pragma unroll 1
        for (; j + 4 <= c; j += 4) {
            int s0 = __shfl(cv, hb + j);
            int s1 = __shfl(cv, hb + j + 1);
            int s2 = __shfl(cv, hb + j + 2);
            int s3 = __shfl(cv, hb + j + 3);
            float w0 = __shfl(wv, hb + j);
            float w1 = __shfl(wv, hb + j + 1);
            float w2 = __shfl(wv, hb + j + 2);
            float w3 = __shfl(wv, hb + j + 3);
            uint2v v0 = h2[(size_t)s0 * 32 + sl];
            uint2v v1 = h2[(size_t)s1 * 32 + sl];
            uint2v v2 = h2[(size_t)s2 * 32 + sl];
            uint2v v3 = h2[(size_t)s3 * 32 + sl];
            a += w0 * dec(v0); a += w1 * dec(v1); a += w2 * dec(v2); a += w3 * dec(v3);
        }
#pragma unroll 1
        for (; j < c; ++j) {
            int s = __shfl(cv, hb + j);
            float wgt = __shfl(wv, hb + j);
            a += wgt * dec(h2[(size_t)s * 32 + sl]);
        }
    }

    // un-permute: a.{x,z} -> cols (c0, c0+1); a.{y,w} -> cols (c0+16, c0+17)
    int u = sl >> 3;
    int m = (sl & 7) * 2;
    int c0 = u * 32 + m;
    f2 b0 = *(const f2*)(bias + c0);
    f2 b1 = *(const f2*)(bias + c0 + 16);
    f2 o0, o1;
    o0.x = di * a.x + b0.x;
    o0.y = di * a.z + b0.y;
    o1.x = di * a.y + b1.x;
    o1.y = di * a.w + b1.y;
    if (relu) {
        o0.x = fmaxf(o0.x, 0.0f);
        o0.y = fmaxf(o0.y, 0.0f);
        o1.x = fmaxf(o1.x, 0.0f);
        o1.y = fmaxf(o1.y, 0.0f);
    }
    float* orow = out + (size_t)n * FDIM;
    *(f2*)(orow + c0) = o0;
    *(f2*)(orow + c0 + 16) = o1;
    if (out2) {
        float* orow2 = out2 + (size_t)n * FDIM;
        *(f2*)(orow2 + c0) = o0;
        *(f2*)(orow2 + c0 + 16) = o1;
    }
}

extern "C" void kernel_launch(void* const* d_in, const int* in_sizes, int n_in,
                              void* d_out, int out_size, void* d_ws, size_t ws_size,
                              hipStream_t stream) {
    const float* x  = (const float*)d_in[0];
    const int*   ei = (const int*)d_in[1];
    const float* W1 = (const float*)d_in[2];
    const float* b1 = (const float*)d_in[3];
    const float* W2 = (const float*)d_in[4];
    const float* b2 = (const float*)d_in[5];
    const float* W3 = (const float*)d_in[6];
    const float* b3 = (const float*)d_in[7];
    int E = in_sizes[1] / 2;
    const int* srcp = ei;
    const int* dstp = ei + E;
    float* outf = (float*)d_out;

    // workspace layout (~21.2 MB)
    unsigned* hpk = (unsigned*)d_ws;                          // N*64 uints, 12.8 MB
    int*      fill = (int*)(hpk + (size_t)NNODES * 64);       // N ints
    int*      col  = fill + NNODES;                           // N*KELL ints (8 MB)
    unsigned* wpk  = (unsigned*)(col + (size_t)NNODES * KELL);// 3*16384 uints
    float*    bufB = outf;  // first half of d_out doubles as ping-pong scratch

    (void)hipMemsetAsync(fill, 0, sizeof(int) * NNODES, stream);

    int eb = (E / 2 + 255) / 256;
    int gb = (NNODES + 63) / 64;               // 782 GEMM blocks
    int ab = (NNODES / 2 * 64 + 255) / 256;    // 6250 agg blocks (2 nodes/wave)

    k_prepw<<<dim3(32, 3), 256, 0, stream>>>(W1, W2, W3, wpk);
    k_fill<<<eb, 256, 0, stream>>>(srcp, dstp, fill, col, E);

    k_gemm<<<gb, 256, 0, stream>>>(x, wpk, hpk, NNODES);
    k_agg<<<ab, 256, 0, stream>>>(hpk, fill, col, b1, bufB, nullptr, 1);
    k_gemm<<<gb, 256, 0, stream>>>(bufB, wpk + 16384, hpk, NNODES);
    k_agg<<<ab, 256, 0, stream>>>(hpk, fill, col, b2, bufB, nullptr, 1);
    k_gemm<<<gb, 256, 0, stream>>>(bufB, wpk + 32768, hpk, NNODES);
    k_agg<<<ab, 256, 0, stream>>>(hpk, fill, col, b3, outf,
                                  outf + (size_t)NNODES * FDIM, 0);
}

// Round 2
// 249.320 us; speedup vs baseline: 1.2657x; 1.0218x over previous
//
#include <hip/hip_runtime.h>

#define NNODES 50000
#define FDIM 128
#define KELL 40

typedef float f4 __attribute__((ext_vector_type(4)));
typedef float f2 __attribute__((ext_vector_type(2)));
typedef short short8 __attribute__((ext_vector_type(8)));
typedef uint uint4v __attribute__((ext_vector_type(4)));
typedef uint uint2v __attribute__((ext_vector_type(2)));

// ---- single-pass ELL fill, 2 edges/thread for atomic MLP ----
// Degrees ~Poisson(12): P(deg>40)*50k ~ 5e-6, slot clamped for safety.
__global__ __launch_bounds__(256) void k_fill(const int* __restrict__ src,
                                              const int* __restrict__ dst,
                                              int* __restrict__ fill,
                                              int* __restrict__ col, int E) {
    int i = blockIdx.x * 256 + threadIdx.x;
    int e0 = i * 2;
    if (e0 + 1 < E) {
        int2 s2 = *(const int2*)(src + e0);
        int2 d2 = *(const int2*)(dst + e0);
        int slot0 = atomicAdd(&fill[d2.x], 1);
        int slot1 = atomicAdd(&fill[d2.y], 1);
        if (slot0 < KELL) col[d2.x * KELL + slot0] = s2.x;
        if (slot1 < KELL) col[d2.y * KELL + slot1] = s2.y;
    } else if (e0 < E) {
        int d = dst[e0];
        int slot = atomicAdd(&fill[d], 1);
        if (slot < KELL) col[d * KELL + slot] = src[e0];
    }
}

// ---- split one f32 pair into packed truncated-bf16 hi / lo words ----
__device__ __forceinline__ void split2(float x0, float x1, unsigned& hi, unsigned& lo) {
    unsigned u0 = __float_as_uint(x0), u1 = __float_as_uint(x1);
    unsigned h0 = u0 & 0xffff0000u, h1 = u1 & 0xffff0000u;
    hi = h1 | (h0 >> 16);
    float l0 = x0 - __uint_as_float(h0);
    float l1 = x1 - __uint_as_float(h1);
    lo = (__float_as_uint(l1) & 0xffff0000u) | (__float_as_uint(l0) >> 16);
}

// ---- pack two f32 accumulators into one uint of 2x RTNE bf16 ----
__device__ __forceinline__ unsigned pack2(float lo, float hi) {
    unsigned ul = __float_as_uint(lo);
    unsigned uh = __float_as_uint(hi);
    ul += 0x7fffu + ((ul >> 16) & 1u);   // round-to-nearest-even into bf16
    uh += 0x7fffu + ((uh >> 16) & 1u);
    return (ul >> 16) | (uh & 0xffff0000u);
}

// ---- decode a gathered uint2 (4 packed bf16) back to f4 ----
__device__ __forceinline__ f4 dec(uint2v v) {
    f4 r;
    r.x = __uint_as_float(v.x << 16);
    r.y = __uint_as_float(v.x & 0xffff0000u);
    r.z = __uint_as_float(v.y << 16);
    r.w = __uint_as_float(v.y & 0xffff0000u);
    return r;
}

// ---- W pre-split into MFMA B-fragment order (hi 8192 uints, lo 8192 uints) ----
// B-frag for mfma_f32_16x16x32_bf16: lane l, reg j holds W[k][n],
// k=(l>>4)*8+j+32*s, n=t*16+(l&15). Packed record: uint p = ((s*8+t)*64+l)*4+jp
// holds bf16 pair (j=2jp, 2jp+1) -> lane-contiguous dwordx4, L2-broadcast.
__global__ __launch_bounds__(256) void k_prepw(const float* __restrict__ W1,
                                               const float* __restrict__ W2,
                                               const float* __restrict__ W3,
                                               unsigned* __restrict__ wpk) {
    int y = blockIdx.y;
    const float* W = (y == 0) ? W1 : (y == 1) ? W2 : W3;
    unsigned* dh = wpk + (size_t)y * 16384;
    unsigned* dl = dh + 8192;
    int p = blockIdx.x * 256 + threadIdx.x;     // 0..8191
    int jp = p & 3;
    int l = (p >> 2) & 63;
    int st = p >> 8;                            // s*8 + t
    int s = st >> 3, t = st & 7;
    int k0 = ((l >> 4) << 3) + (jp << 1) + (s << 5);
    int n = (t << 4) + (l & 15);
    float x0 = W[k0 * 128 + n];
    float x1 = W[(k0 + 1) * 128 + n];
    unsigned hi, lo;
    split2(x0, x1, hi, lo);
    dh[p] = hi;
    dl[p] = lo;
}

// ---- layer-1 MFMA GEMM: f32 A from global, W-frags stream from L2 ----
// Fully unrolled (static register indices only). Output packed bf16 col-pairs.
__global__ __launch_bounds__(256, 4) void k_gemm(const float* __restrict__ A,
                                                 const unsigned* __restrict__ wsrc,
                                                 unsigned* __restrict__ H, int nrows) {
    int tid = threadIdx.x;
    int w = tid >> 6, l = tid & 63;
    int m16 = l & 15, q = l >> 4;
    int rbase = blockIdx.x * 64 + w * 16;
    int row = rbase + m16;
    int rowc = row > nrows - 1 ? nrows - 1 : row;

    union u8 { unsigned u[4]; uint4v uv; short8 v; };
    u8 ah[4], al[4];
    const f4* A4 = (const f4*)A;
#pragma unroll
    for (int s = 0; s < 4; ++s) {
        f4 a0 = A4[(size_t)rowc * 32 + s * 8 + q * 2];
        f4 a1 = A4[(size_t)rowc * 32 + s * 8 + q * 2 + 1];
        split2(a0.x, a0.y, ah[s].u[0], al[s].u[0]);
        split2(a0.z, a0.w, ah[s].u[1], al[s].u[1]);
        split2(a1.x, a1.y, ah[s].u[2], al[s].u[2]);
        split2(a1.z, a1.w, ah[s].u[3], al[s].u[3]);
    }

    f4 acc[8];
#pragma unroll
    for (int t = 0; t < 8; ++t) acc[t] = (f4)0.0f;

    const uint4v* wg4 = (const uint4v*)wsrc;    // hi: [0,2048) lo: [2048,4096)
#pragma unroll
    for (int s = 0; s < 4; ++s) {
#pragma unroll
        for (int t = 0; t < 8; ++t) {
            u8 bh, bl;
            bh.uv = wg4[(s * 8 + t) * 64 + l];
            bl.uv = wg4[2048 + (s * 8 + t) * 64 + l];
            acc[t] = __builtin_amdgcn_mfma_f32_16x16x32_bf16(ah[s].v, bh.v, acc[t], 0, 0, 0);
            acc[t] = __builtin_amdgcn_mfma_f32_16x16x32_bf16(al[s].v, bh.v, acc[t], 0, 0, 0);
            acc[t] = __builtin_amdgcn_mfma_f32_16x16x32_bf16(ah[s].v, bl.v, acc[t], 0, 0, 0);
        }
    }

    // D layout: col = lane&15, row = (lane>>4)*4 + reg; pack col pair -> uint
#pragma unroll
    for (int up = 0; up < 4; ++up) {
#pragma unroll
        for (int r = 0; r < 4; ++r) {
            int rr = rbase + q * 4 + r;
            if (rr < nrows)
                H[(size_t)rr * 64 + up * 16 + m16] =
                    pack2(acc[2 * up][r], acc[2 * up + 1][r]);
        }
    }
}

// ---- FUSED agg(+bias+relu) -> gemm for layer boundaries 1->2 and 2->3 ----
// Each wave aggregates its OWN 16 nodes (2 per iteration, 32 lanes/node),
// stages the 16x128 f32 tile in LDS (row pad 128->132 words: ds_read_b128
// lands at the 8-way minimum aliasing instead of 16-way), then runs the
// MFMA GEMM on exactly those rows. No cross-wave sharing -> NO barrier:
// producer lanes and consumer lanes are the same wave (DS unit is in-order
// per wave). Deletes the 25.6MB f32 write + 25.6MB read per boundary.
__global__ __launch_bounds__(256, 4) void k_agg_gemm(const unsigned* __restrict__ hin,
                                                     const int* __restrict__ fill,
                                                     const int* __restrict__ col,
                                                     const float* __restrict__ bias,
                                                     const unsigned* __restrict__ wsrc,
                                                     unsigned* __restrict__ hout) {
    __shared__ float As[64][132];
    int tid = threadIdx.x;
    int w = tid >> 6, l = tid & 63;
    int half = l >> 5;
    int sl = l & 31;
    int hb = half * 32;
    int nbase = blockIdx.x * 64 + w * 16;

    const uint2v* h2 = (const uint2v*)hin;
#pragma unroll 1
    for (int it = 0; it < 8; ++it) {
        int n = nbase + it * 2 + half;
        int nc = n >= NNODES ? NNODES - 1 : n;   // clamp; rows >= N never stored
        int deg = fill[nc];
        int c = deg < KELL ? deg : KELL;
        float di = rsqrtf(1.0f + (float)deg);
        f4 a = di * dec(h2[(size_t)nc * 32 + sl]);

        int beg = nc * KELL;
        int cv = 0;
        float wv = 0.0f;
        if (sl < c) {
            cv = col[beg + sl];
            wv = rsqrtf(1.0f + (float)fill[cv]);
        }
        int j = 0;
#pragma unroll 1
        for (; j + 8 <= c; j += 8) {
            int s0 = __shfl(cv, hb + j);
            int s1 = __shfl(cv, hb + j + 1);
            int s2 = __shfl(cv, hb + j + 2);
            int s3 = __shfl(cv, hb + j + 3);
            int s4 = __shfl(cv, hb + j + 4);
            int s5 = __shfl(cv, hb + j + 5);
            int s6 = __shfl(cv, hb + j + 6);
            int s7 = __shfl(cv, hb + j + 7);
            float w0 = __shfl(wv, hb + j);
            float w1 = __shfl(wv, hb + j + 1);
            float w2 = __shfl(wv, hb + j + 2);
            float w3 = __shfl(wv, hb + j + 3);
            float w4 = __shfl(wv, hb + j + 4);
            float w5 = __shfl(wv, hb + j + 5);
            float w6 = __shfl(wv, hb + j + 6);
            float w7 = __shfl(wv, hb + j + 7);
            uint2v v0 = h2[(size_t)s0 * 32 + sl];
            uint2v v1 = h2[(size_t)s1 * 32 + sl];
            uint2v v2 = h2[(size_t)s2 * 32 + sl];
            uint2v v3 = h2[(size_t)s3 * 32 + sl];
            uint2v v4 = h2[(size_t)s4 * 32 + sl];
            uint2v v5 = h2[(size_t)s5 * 32 + sl];
            uint2v v6 = h2[(size_t)s6 * 32 + sl];
            uint2v v7 = h2[(size_t)s7 * 32 + sl];
            a += w0 * dec(v0); a += w1 * dec(v1); a += w2 * dec(v2); a += w3 * dec(v3);
            a += w4 * dec(v4); a += w5 * dec(v5); a += w6 * dec(v6); a += w7 * dec(v7);
        }
#pragma unroll 1
        for (; j + 4 <= c; j += 4) {
            int s0 = __shfl(cv, hb + j);
            int s1 = __shfl(cv, hb + j + 1);
            int s2 = __shfl(cv, hb + j + 2);
            int s3 = __shfl(cv, hb + j + 3);
            float w0 = __shfl(wv, hb + j);
            float w1 = __shfl(wv, hb + j + 1);
            float w2 = __shfl(wv, hb + j + 2);
            float w3 = __shfl(wv, hb + j + 3);
            uint2v v0 = h2[(size_t)s0 * 32 + sl];
            uint2v v1 = h2[(size_t)s1 * 32 + sl];
            uint2v v2 = h2[(size_t)s2 * 32 + sl];
            uint2v v3 = h2[(size_t)s3 * 32 + sl];
            a += w0 * dec(v0); a += w1 * dec(v1); a += w2 * dec(v2); a += w3 * dec(v3);
        }
#pragma unroll 1
        for (; j < c; ++j) {
            int s = __shfl(cv, hb + j);
            float wgt = __shfl(wv, hb + j);
            a += wgt * dec(h2[(size_t)s * 32 + sl]);
        }

        // un-permute + bias + relu -> wave-private LDS tile row
        int u = sl >> 3;
        int m = (sl & 7) * 2;
        int c0 = u * 32 + m;
        f2 b0 = *(const f2*)(bias + c0);
        f2 b1v = *(const f2*)(bias + c0 + 16);
        f2 o0, o1;
        o0.x = fmaxf(di * a.x + b0.x, 0.0f);
        o0.y = fmaxf(di * a.z + b0.y, 0.0f);
        o1.x = fmaxf(di * a.y + b1v.x, 0.0f);
        o1.y = fmaxf(di * a.w + b1v.y, 0.0f);
        int rl = w * 16 + it * 2 + half;
        *(f2*)&As[rl][c0] = o0;
        *(f2*)&As[rl][c0 + 16] = o1;
    }

    // ---- gemm phase on this wave's own 16 rows (no barrier needed) ----
    int m16 = l & 15, q = l >> 4;
    int rl = w * 16 + m16;
    union u8 { unsigned u[4]; uint4v uv; short8 v; };
    u8 ah[4], al[4];
#pragma unroll
    for (int s = 0; s < 4; ++s) {
        f4 a0 = *(const f4*)&As[rl][s * 32 + q * 8];
        f4 a1 = *(const f4*)&As[rl][s * 32 + q * 8 + 4];
        split2(a0.x, a0.y, ah[s].u[0], al[s].u[0]);
        split2(a0.z, a0.w, ah[s].u[1], al[s].u[1]);
        split2(a1.x, a1.y, ah[s].u[2], al[s].u[2]);
        split2(a1.z, a1.w, ah[s].u[3], al[s].u[3]);
    }

    f4 acc[8];
#pragma unroll
    for (int t = 0; t < 8; ++t) acc[t] = (f4)0.0f;

    const uint4v* wg4 = (const uint4v*)wsrc;
#pragma unroll
    for (int s = 0; s < 4; ++s) {
#pragma unroll
        for (int t = 0; t < 8; ++t) {
            u8 bh, bl;
            bh.uv = wg4[(s * 8 + t) * 64 + l];
            bl.uv = wg4[2048 + (s * 8 + t) * 64 + l];
            acc[t] = __builtin_amdgcn_mfma_f32_16x16x32_bf16(ah[s].v, bh.v, acc[t], 0, 0, 0);
            acc[t] = __builtin_amdgcn_mfma_f32_16x16x32_bf16(al[s].v, bh.v, acc[t], 0, 0, 0);
            acc[t] = __builtin_amdgcn_mfma_f32_16x16x32_bf16(ah[s].v, bl.v, acc[t], 0, 0, 0);
        }
    }

    int rbase = blockIdx.x * 64 + w * 16;
#pragma unroll
    for (int up = 0; up < 4; ++up) {
#pragma unroll
        for (int r = 0; r < 4; ++r) {
            int rr = rbase + q * 4 + r;
            if (rr < NNODES)
                hout[(size_t)rr * 64 + up * 16 + m16] =
                    pack2(acc[2 * up][r], acc[2 * up + 1][r]);
        }
    }
}

// ---- final aggregation: packed-bf16 gather -> f32 dual store ----
__global__ __launch_bounds__(256) void k_agg(const unsigned* __restrict__ hpk,
                                             const int* __restrict__ fill,
                                             const int* __restrict__ col,
                                             const float* __restrict__ bias,
                                             float* __restrict__ out,
                                             float* __restrict__ out2, int relu) {
    int gw = (blockIdx.x * 256 + threadIdx.x) >> 6;
    int lane = threadIdx.x & 63;
    int half = lane >> 5;
    int sl = lane & 31;
    int hb = half * 32;
    int n = gw * 2 + half;
    if (n >= NNODES) return;
    int deg = fill[n];
    int c = deg < KELL ? deg : KELL;
    float di = rsqrtf(1.0f + (float)deg);

    const uint2v* h2 = (const uint2v*)hpk;
    f4 a = di * dec(h2[(size_t)n * 32 + sl]);

    int beg = n * KELL;
    {
        int cv = 0;
        float wv = 0.0f;
        if (sl < c) {
            cv = col[beg + sl];
            wv = rsqrtf(1.0f + (float)fill[cv]);
        }
        int j = 0;
#pragma unroll 1
        for (; j + 8 <= c; j += 8) {
            int s0 = __shfl(cv, hb + j);
            int s1 = __shfl(cv, hb + j + 1);
            int s2 = __shfl(cv, hb + j + 2);
            int s3 = __shfl(cv, hb + j + 3);
            int s4 = __shfl(cv, hb + j + 4);
            int s5 = __shfl(cv, hb + j + 5);
            int s6 = __shfl(cv, hb + j + 6);
            int s7 = __shfl(cv, hb + j + 7);
            float w0 = __shfl(wv, hb + j);
            float w1 = __shfl(wv, hb + j + 1);
            float w2 = __shfl(wv, hb + j + 2);
            float w3 = __shfl(wv, hb + j + 3);
            float w4 = __shfl(wv, hb + j + 4);
            float w5 = __shfl(wv, hb + j + 5);
            float w6 = __shfl(wv, hb + j + 6);
            float w7 = __shfl(wv, hb + j + 7);
            uint2v v0 = h2[(size_t)s0 * 32 + sl];
            uint2v v1 = h2[(size_t)s1 * 32 + sl];
            uint2v v2 = h2[(size_t)s2 * 32 + sl];
            uint2v v3 = h2[(size_t)s3 * 32 + sl];
            uint2v v4 = h2[(size_t)s4 * 32 + sl];
            uint2v v5 = h2[(size_t)s5 * 32 + sl];
            uint2v v6 = h2[(size_t)s6 * 32 + sl];
            uint2v v7 = h2[(size_t)s7 * 32 + sl];
            a += w0 * dec(v0); a += w1 * dec(v1); a += w2 * dec(v2); a += w3 * dec(v3);
            a += w4 * dec(v4); a += w5 * dec(v5); a += w6 * dec(v6); a += w7 * dec(v7);
        }
#pragma unroll 1
        for (; j + 4 <= c; j += 4) {
            int s0 = __shfl(cv, hb + j);
            int s1 = __shfl(cv, hb + j + 1);
            int s2 = __shfl(cv, hb + j + 2);
            int s3 = __shfl(cv, hb + j + 3);
            float w0 = __shfl(wv, hb + j);
            float w1 = __shfl(wv, hb + j + 1);
            float w2 = __shfl(wv, hb + j + 2);
            float w3 = __shfl(wv, hb + j + 3);
            uint2v v0 = h2[(size_t)s0 * 32 + sl];
            uint2v v1 = h2[(size_t)s1 * 32 + sl];
            uint2v v2 = h2[(size_t)s2 * 32 + sl];
            uint2v v3 = h2[(size_t)s3 * 32 + sl];
            a += w0 * dec(v0); a += w1 * dec(v1); a += w2 * dec(v2); a += w3 * dec(v3);
        }
#pragma unroll 1
        for (; j < c; ++j) {
            int s = __shfl(cv, hb + j);
            float wgt = __shfl(wv, hb + j);
            a += wgt * dec(h2[(size_t)s * 32 + sl]);
        }
    }

    // un-permute: a.{x,z} -> cols (c0, c0+1); a.{y,w} -> cols (c0+16, c0+17)
    int u = sl >> 3;
    int m = (sl & 7) * 2;
    int c0 = u * 32 + m;
    f2 b0 = *(const f2*)(bias + c0);
    f2 b1 = *(const f2*)(bias + c0 + 16);
    f2 o0, o1;
    o0.x = di * a.x + b0.x;
    o0.y = di * a.z + b0.y;
    o1.x = di * a.y + b1.x;
    o1.y = di * a.w + b1.y;
    if (relu) {
        o0.x = fmaxf(o0.x, 0.0f);
        o0.y = fmaxf(o0.y, 0.0f);
        o1.x = fmaxf(o1.x, 0.0f);
        o1.y = fmaxf(o1.y, 0.0f);
    }
    float* orow = out + (size_t)n * FDIM;
    *(f2*)(orow + c0) = o0;
    *(f2*)(orow + c0 + 16) = o1;
    if (out2) {
        float* orow2 = out2 + (size_t)n * FDIM;
        *(f2*)(orow2 + c0) = o0;
        *(f2*)(orow2 + c0 + 16) = o1;
    }
}

extern "C" void kernel_launch(void* const* d_in, const int* in_sizes, int n_in,
                              void* d_out, int out_size, void* d_ws, size_t ws_size,
                              hipStream_t stream) {
    const float* x  = (const float*)d_in[0];
    const int*   ei = (const int*)d_in[1];
    const float* W1 = (const float*)d_in[2];
    const float* b1 = (const float*)d_in[3];
    const float* W2 = (const float*)d_in[4];
    const float* b2 = (const float*)d_in[5];
    const float* W3 = (const float*)d_in[6];
    const float* b3 = (const float*)d_in[7];
    int E = in_sizes[1] / 2;
    const int* srcp = ei;
    const int* dstp = ei + E;
    float* outf = (float*)d_out;

    // workspace layout (~21.2 MB)
    unsigned* hpkA = (unsigned*)d_ws;                          // N*64 uints, 12.8 MB
    int*      fill = (int*)(hpkA + (size_t)NNODES * 64);       // N ints
    int*      col  = fill + NNODES;                            // N*KELL ints (8 MB)
    unsigned* wpk  = (unsigned*)(col + (size_t)NNODES * KELL); // 3*16384 uints
    // second packed-h ping-pong buffer lives in d_out's (unused-until-final)
    // first half: 12.8 MB < 25.6 MB, fully overwritten by the final k_agg.
    unsigned* hpkB = (unsigned*)outf;

    (void)hipMemsetAsync(fill, 0, sizeof(int) * NNODES, stream);

    int eb = (E / 2 + 255) / 256;
    int gb = (NNODES + 63) / 64;               // 782 blocks (gemm / fused)
    int ab = (NNODES / 2 * 64 + 255) / 256;    // 6250 agg blocks (2 nodes/wave)

    k_prepw<<<dim3(32, 3), 256, 0, stream>>>(W1, W2, W3, wpk);
    k_fill<<<eb, 256, 0, stream>>>(srcp, dstp, fill, col, E);

    k_gemm<<<gb, 256, 0, stream>>>(x, wpk, hpkA, NNODES);
    k_agg_gemm<<<gb, 256, 0, stream>>>(hpkA, fill, col, b1, wpk + 16384, hpkB);
    k_agg_gemm<<<gb, 256, 0, stream>>>(hpkB, fill, col, b2, wpk + 32768, hpkA);
    k_agg<<<ab, 256, 0, stream>>>(hpkA, fill, col, b3, outf,
                                  outf + (size_t)NNODES * FDIM, 0);
}